// Round 5
// baseline (99.726 us; speedup 1.0000x reference)
//
#include <hip/hip_runtime.h>
#include <math.h>

#define NT_ 365
#define NS_ 1024
#define NH_ 64
#define NG_ 32
#define NW_ 514        // NH*8 + 2
#define CH_ 64         // timesteps per chunk
#define NCHUNK_ 6      // ceil(365/64); tail steps are harmless dummies
#define YPAD_ 65       // padded ytile row stride: conflict-free R/W
#define SUB_ 4         // met sub-chunk: register double-buffer depth (x2 sites)

__device__ __forceinline__ float sigmoidf(float v) {
  return 1.0f / (1.0f + expf(-v));
}

// met = (Ps, Pl, relu(Ta), E); relu folded here since gm > 0
__device__ __forceinline__ float4 compute_met(float4 xv) {
  const float P = xv.x, E = xv.y, T1 = xv.z, T2 = xv.w;
  const float Ta = (T1 + T2) * 0.5f;
  float rP;
  if (T2 <= 0.0f) {
    rP = 0.0f;
  } else if (T1 >= 0.0f) {
    rP = 1.0f;
  } else {
    float r = (T1 + T2) / (T2 - T1);
    r = fminf(fmaxf(r, -0.999999f), 0.999999f);
    rP = 1.0f - acosf(r) * (1.0f / 3.1415f);
  }
  float4 m;
  m.x = (1.0f - rP) * P;   // Ps
  m.y = rP * P;            // Pl
  m.z = fmaxf(Ta, 0.0f);   // relu(Ta)
  m.w = E;
  return m;
}

struct Gates {
  float gm, nge, gi;          // snow chain
  float gl, mgo, kb1m, gbgo;  // H/G chain
  float ga, c1, c2, qb;       // y = ga*Hh + c1*M + c2*G; qb added at store
};

// TWO-SITE INTERLEAVE. Evidence: R3 showed two co-resident waves interleave
// for free (2x work per SIMD, same 44 us) -> a solo in-order wave issues at
// ~8 cyc/inst, dominated by dep-stall gaps that an independent stream can
// fill. So give ONE wave two independent streams: sites A and B stepped
// alternately (lane = hidden unit for both). B's instructions fill A's dep
// gaps and vice versa -> effective spacing ~halves. No barriers, no LDS
// handoff, no packing penalty: 512 waves spread at <=1 wave/SIMD.
__global__ __launch_bounds__(128) void waternet_scan(
    const float* __restrict__ x,     // [NT, NS, 4]
    const float* __restrict__ xc,    // [NS, NG]
    const float* __restrict__ fc_w,  // [NW, NG]
    const float* __restrict__ fc_b,  // [NW]
    float* __restrict__ out)         // [NT, NS]
{
  __shared__ float4 smet[4][CH_];          // 4 KB:  [slot][step] met
  __shared__ float  ytile[4][CH_ * YPAD_]; // 66.6 KB: per-slot y rows

  const int tid  = threadIdx.x;
  const int lane = tid & 63;
  const int wv   = tid >> 6;               // 0..1
  const int ssA  = wv * 2, ssB = ssA + 1;  // LDS slots for this wave's 2 sites
  const int siteA = (blockIdx.x << 2) + ssA;
  const int siteB = siteA + 1;             // adjacent: shared cache lines
  const int uA = __builtin_amdgcn_readfirstlane(siteA);
  const float4* xp  = (const float4*)x;
  const float4* wq4 = (const float4*)fc_w;

  // chunk-0 prefetch first: HBM latency hides under the gate GEMM
  float4 xcA = xp[lane * NS_ + siteA];
  float4 xcB = xp[lane * NS_ + siteB];

  // ---- prologue GEMM for BOTH sites, sharing every fc_w load
  float aA[8], aB[8];
#pragma unroll
  for (int k = 0; k < 8; ++k) { aA[k] = fc_b[k * NH_ + lane]; aB[k] = aA[k]; }
  float aqA = fc_b[NW_ - 1], aqB = aqA;

  const float4* xcqA = (const float4*)(xc + uA * NG_);
  const float4* xcqB = (const float4*)(xc + (uA + 1) * NG_);
#pragma unroll
  for (int g4 = 0; g4 < NG_ / 4; ++g4) {
    const float4 xA = xcqA[g4];
    const float4 xB = xcqB[g4];
#pragma unroll
    for (int k = 0; k < 8; ++k) {
      const float4 w = wq4[(k * NH_ + lane) * (NG_ / 4) + g4];
      aA[k] = fmaf(xA.x, w.x, aA[k]); aA[k] = fmaf(xA.y, w.y, aA[k]);
      aA[k] = fmaf(xA.z, w.z, aA[k]); aA[k] = fmaf(xA.w, w.w, aA[k]);
      aB[k] = fmaf(xB.x, w.x, aB[k]); aB[k] = fmaf(xB.y, w.y, aB[k]);
      aB[k] = fmaf(xB.z, w.z, aB[k]); aB[k] = fmaf(xB.w, w.w, aB[k]);
    }
    {
      const float4 w = wq4[(NW_ - 1) * (NG_ / 4) + g4];
      aqA = fmaf(xA.x, w.x, aqA); aqA = fmaf(xA.y, w.y, aqA);
      aqA = fmaf(xA.z, w.z, aqA); aqA = fmaf(xA.w, w.w, aqA);
      aqB = fmaf(xB.x, w.x, aqB); aqB = fmaf(xB.y, w.y, aqB);
      aqB = fmaf(xB.z, w.z, aqB); aqB = fmaf(xB.w, w.w, aqB);
    }
  }

  // ---- gates (per-lane = per hidden unit), folded constants
  auto mkgates = [&](const float a[8], float aq) -> Gates {
    Gates g;
    g.gm  = expf(a[0]) + 1.0f;
    g.nge = -2.0f * sigmoidf(a[1]);          // -ge
    const float go = sigmoidf(a[2]);
    g.gl  = expf(a[3] * 2.0f);
    float mx = a[4];
#pragma unroll
    for (int mm = 32; mm >= 1; mm >>= 1) mx = fmaxf(mx, __shfl_xor(mx, mm, 64));
    const float ex = expf(a[4] - mx);
    float sm = ex;
#pragma unroll
    for (int mm = 32; mm >= 1; mm >>= 1) sm += __shfl_xor(sm, mm, 64);
    g.ga = ex / sm;
    const float gb = sigmoidf(a[5]);
    const float kb = sigmoidf(a[6]) * 0.1f;
    g.gi   = sigmoidf(a[7]);
    g.qb   = fmaxf(aq, 0.0f) * (1.0f / NH_);
    g.mgo  = -go;
    g.kb1m = 1.0f - kb;
    g.gbgo = gb * go;
    g.c1 = g.ga * (go * (1.0f - gb) - 1.0f);
    g.c2 = g.ga * kb;
    return g;
  };
  const Gates gA = mkgates(aA, aqA);
  const Gates gB = mkgates(aB, aqB);

  // ---- scan state, both sites
  float S0A = 0.f, H0A = 0.f, GA = 0.f;
  float S0B = 0.f, H0B = 0.f, GB = 0.f;

  // stage chunk-0 met (lane = step); per-wave slots + in-order DS -> no barrier
  smet[ssA][lane] = compute_met(xcA);
  smet[ssB][lane] = compute_met(xcB);

  // one fused step: snow (3-deep S cycle) + H (4-deep cycle) + G + y.
  // ~17 VALU + 1 ds_write; the two sites' calls interleave at the scheduler.
  auto pstep = [&](const Gates& g, float& S0, float& H0, float& G,
                   const float4 m, float* ywaddr) {
    const float melt = m.z * g.gm;
    const float r    = fmaxf(S0 - melt, 0.0f);       // S0 - Sm
    const float Sm   = S0 - r;                       // min(S0, melt)
    const float d    = fmaf(m.y, g.gi, fmaf(m.w, g.nge, Sm));
    S0 = r + m.x;
    const float z  = H0 + d;
    const float Hh = fmaxf(z, 0.0f);                     // H
    const float M  = __builtin_amdgcn_fmed3f(z, 0.0f, g.gl);  // min(H, gl)
    H0 = fminf(fmaf(g.mgo, M, Hh), g.gl);                // min(H - go*M, gl)
    G  = fmaf(g.kb1m, G, g.gbgo * M);                    // pre-drain G
    *ywaddr = fmaf(g.c2, G, fmaf(g.c1, M, g.ga * Hh));
  };

  float*       ywA = &ytile[ssA][lane];
  float*       ywB = &ytile[ssB][lane];
  const float* yrA = &ytile[ssA][lane * YPAD_];
  const float* yrB = &ytile[ssB][lane * YPAD_];

#pragma unroll 1   // keep body I-cache resident across 6 iterations
  for (int c = 0; c < NCHUNK_; ++c) {
    // prefetch chunk c+1 from HBM (clamped dummy tail) — in flight all chunk
    int tn = (c + 1) * CH_ + lane;
    tn = (tn < NT_) ? tn : (NT_ - 1);
    const float4 xnA = xp[tn * NS_ + siteA];
    const float4 xnB = xp[tn * NS_ + siteB];

    const float4* mpA = &smet[ssA][0];
    const float4* mpB = &smet[ssB][0];

    // ---- 4-step register double-buffer per site: loads for sub-chunk k+1
    // issue before sub-chunk k's compute -> ds_read latency covered.
    float4 mA0[SUB_], mA1[SUB_], mB0[SUB_], mB1[SUB_];
#pragma unroll
    for (int u = 0; u < SUB_; ++u) { mA0[u] = mpA[u]; mB0[u] = mpB[u]; }

#pragma unroll
    for (int sc = 0; sc < CH_ / SUB_; ++sc) {
      float4* cA = (sc & 1) ? mA1 : mA0;
      float4* nA = (sc & 1) ? mA0 : mA1;
      float4* cB = (sc & 1) ? mB1 : mB0;
      float4* nB = (sc & 1) ? mB0 : mB1;
      if (sc < CH_ / SUB_ - 1) {
#pragma unroll
        for (int u = 0; u < SUB_; ++u) {
          nA[u] = mpA[SUB_ * (sc + 1) + u];
          nB[u] = mpB[SUB_ * (sc + 1) + u];
        }
      }
#pragma unroll
      for (int u = 0; u < SUB_; ++u) {
        const int j = SUB_ * sc + u;
        pstep(gA, S0A, H0A, GA, cA[u], ywA + j * YPAD_);  // independent
        pstep(gB, S0B, H0B, GB, cB[u], ywB + j * YPAD_);  // streams fill
      }                                                   // each other's gaps
    }

    // ---- transposed reduction, both sites (bank=(t'+h)%32, conflict-free)
    float rA0 = 0.f, rA1 = 0.f, rA2 = 0.f, rA3 = 0.f;
    float rB0 = 0.f, rB1 = 0.f, rB2 = 0.f, rB3 = 0.f;
#pragma unroll
    for (int h = 0; h < CH_; h += 4) {
      rA0 += yrA[h + 0]; rA1 += yrA[h + 1];
      rA2 += yrA[h + 2]; rA3 += yrA[h + 3];
      rB0 += yrB[h + 0]; rB1 += yrB[h + 1];
      rB2 += yrB[h + 2]; rB3 += yrB[h + 3];
    }
    const int t_out = c * CH_ + lane;
    if (t_out < NT_) {
      out[t_out * NS_ + siteA] = ((rA0 + rA1) + (rA2 + rA3)) + gA.qb;
      out[t_out * NS_ + siteB] = ((rB0 + rB1) + (rB2 + rB3)) + gB.qb;
    }

    // stage next chunk's met (reads above already issued -> in-order safe)
    if (c + 1 < NCHUNK_) {
      smet[ssA][lane] = compute_met(xnA);
      smet[ssB][lane] = compute_met(xnB);
    }
  }
}

extern "C" void kernel_launch(void* const* d_in, const int* in_sizes, int n_in,
                              void* d_out, int out_size, void* d_ws, size_t ws_size,
                              hipStream_t stream) {
  const float* x    = (const float*)d_in[0];
  const float* xc   = (const float*)d_in[1];
  const float* fc_w = (const float*)d_in[2];
  const float* fc_b = (const float*)d_in[3];
  float* out = (float*)d_out;

  // 1024 sites, 2 sites per wave, 2 waves per block -> 256 blocks of 128
  // threads, 70.6 KB LDS (<=2 blocks/CU) -> never more than 1 wave/SIMD:
  // all interleaving happens INSIDE each wave, where R3 proved it's free.
  hipLaunchKernelGGL(waternet_scan, dim3(NS_ / 4), dim3(128), 0, stream,
                     x, xc, fc_w, fc_b, out);
}

// Round 6
// 88.587 us; speedup vs baseline: 1.1257x; 1.1257x over previous
//
#include <hip/hip_runtime.h>
#include <math.h>

#define NT_ 365
#define NS_ 1024
#define NH_ 64
#define NG_ 32
#define NW_ 514        // NH*8 + 2
#define CH_ 64         // timesteps per chunk (= wave size)
#define NCHUNK_ 6      // ceil(365/64); tail steps are harmless dummies
#define YPAD_ 65       // padded ytile row stride: conflict-free R/W

__device__ __forceinline__ float sigmoidf(float v) {
  return 1.0f / (1.0f + expf(-v));
}

// broadcast lane l's float to all lanes (imm lane idx in unrolled loops)
__device__ __forceinline__ float rdl(float v, int l) {
  return __int_as_float(__builtin_amdgcn_readlane(__float_as_int(v), l));
}

// met = (Ps, Pl, relu(Ta), E); relu folded here since gm > 0
__device__ __forceinline__ float4 compute_met(float4 xv) {
  const float P = xv.x, E = xv.y, T1 = xv.z, T2 = xv.w;
  const float Ta = (T1 + T2) * 0.5f;
  float rP;
  if (T2 <= 0.0f) {
    rP = 0.0f;
  } else if (T1 >= 0.0f) {
    rP = 1.0f;
  } else {
    float r = (T1 + T2) / (T2 - T1);
    r = fminf(fmaxf(r, -0.999999f), 0.999999f);
    rP = 1.0f - acosf(r) * (1.0f / 3.1415f);
  }
  float4 m;
  m.x = (1.0f - rP) * P;   // Ps
  m.y = rP * P;            // Pl
  m.z = fmaxf(Ta, 0.0f);   // relu(Ta)
  m.w = E;
  return m;
}

// ZERO-DS-READ STEP LOOP. Evidence so far: per-step pacing (~290 cyc) is
// invariant to co-residency (R3), intra-wave ILP (R5), and chain depth alone
// (R2, small gain) -- but the sub-40us kernels (R2/R4) both had fewer LDS
// latency events stranded in the in-order step stream. Theory: an in-order
// wave pays full ds_read->use latency it cannot bury; the met LDS round-trip
// is the residual wall. Fix: met for a 64-step chunk already sits across the
// wave's lanes (lane = t) after the x load -> broadcast per step with
// v_readlane (imm lane, SGPR result, no wait; every consumer uses <=1 SGPR
// operand). Steady state: 4 readlane + ~17 VALU + 1 fire-and-forget ds_write
// per step. No smet, no register double-buffer, no lgkmcnt in the walk.
__global__ __launch_bounds__(256) void waternet_scan(
    const float* __restrict__ x,     // [NT, NS, 4]
    const float* __restrict__ xc,    // [NS, NG]
    const float* __restrict__ fc_w,  // [NW, NG]
    const float* __restrict__ fc_b,  // [NW]
    float* __restrict__ out)         // [NT, NS]
{
  __shared__ float ytile[4][CH_ * YPAD_];  // 66.6 KB: per-wave y rows

  const int tid  = threadIdx.x;
  const int lane = tid & 63;
  const int wv   = tid >> 6;
  const int site = (blockIdx.x << 2) + wv;
  const int us   = __builtin_amdgcn_readfirstlane(site);
  const float4* xp = (const float4*)x;

  // chunk-0 prefetch first: HBM latency hides under the gate GEMM
  float4 xcur = xp[lane * NS_ + site];  // t = lane

  // ---- prologue GEMM: w[site, j] = xc[site,:] . fc_w[j,:] + fc_b[j]
  float acc[8];
#pragma unroll
  for (int k = 0; k < 8; ++k) acc[k] = fc_b[k * NH_ + lane];
  float accq = fc_b[NW_ - 1];

  const float4* xcq = (const float4*)(xc + us * NG_);
  const float4* wq4 = (const float4*)fc_w;
#pragma unroll
  for (int g4 = 0; g4 < NG_ / 4; ++g4) {
    const float4 xv = xcq[g4];
#pragma unroll
    for (int k = 0; k < 8; ++k) {
      const float4 w = wq4[(k * NH_ + lane) * (NG_ / 4) + g4];
      acc[k] = fmaf(xv.x, w.x, acc[k]);
      acc[k] = fmaf(xv.y, w.y, acc[k]);
      acc[k] = fmaf(xv.z, w.z, acc[k]);
      acc[k] = fmaf(xv.w, w.w, acc[k]);
    }
    {
      const float4 w = wq4[(NW_ - 1) * (NG_ / 4) + g4];
      accq = fmaf(xv.x, w.x, accq);
      accq = fmaf(xv.y, w.y, accq);
      accq = fmaf(xv.z, w.z, accq);
      accq = fmaf(xv.w, w.w, accq);
    }
  }

  // ---- gates (per-lane = per hidden unit), folded constants
  const float gm = expf(acc[0]) + 1.0f;
  const float nge = -2.0f * sigmoidf(acc[1]);     // -ge
  const float go = sigmoidf(acc[2]);
  const float gl = expf(acc[3] * 2.0f);
  float mx = acc[4];
#pragma unroll
  for (int mm2 = 32; mm2 >= 1; mm2 >>= 1) mx = fmaxf(mx, __shfl_xor(mx, mm2, 64));
  const float ex = expf(acc[4] - mx);
  float sm = ex;
#pragma unroll
  for (int mm2 = 32; mm2 >= 1; mm2 >>= 1) sm += __shfl_xor(sm, mm2, 64);
  const float ga = ex / sm;
  const float gb = sigmoidf(acc[5]);
  const float kb = sigmoidf(acc[6]) * 0.1f;
  const float gi = sigmoidf(acc[7]);
  const float qb = fmaxf(accq, 0.0f) * (1.0f / NH_);
  const float mgo  = -go;
  const float kb1m = 1.0f - kb;                 // G' = kb1m*G + gbgo*M
  const float gbgo = gb * go;
  const float c1 = ga * (go * (1.0f - gb) - 1.0f);  // y = ga*Hh + c1*M + c2*G
  const float c2 = ga * kb;

  // ---- scan state
  float S0 = 0.0f, H0 = 0.0f, G = 0.0f;

  // met for the CURRENT chunk lives across lanes: lane = local timestep
  float4 mm = compute_met(xcur);

  float*       yw = &ytile[wv][lane];          // step j writes yw[j*YPAD_]
  const float* yr = &ytile[wv][lane * YPAD_];  // reduce: lane sums its row

#pragma unroll 1   // keep body (~11 KB) I-cache resident across 6 iterations
  for (int c = 0; c < NCHUNK_; ++c) {
    // prefetch chunk c+1 from HBM (clamped dummy tail) — in flight all chunk
    int tn = (c + 1) * CH_ + lane;
    tn = (tn < NT_) ? tn : (NT_ - 1);
    const float4 xnext = xp[tn * NS_ + site];

    // ---- 64 steps, pure register compute: 4 readlane + ~17 VALU + 1 ds_write
#pragma unroll
    for (int u = 0; u < CH_; ++u) {
      const float Ps = rdl(mm.x, u);
      const float Pl = rdl(mm.y, u);
      const float Tz = rdl(mm.z, u);
      const float Ev = rdl(mm.w, u);
      const float melt = Tz * gm;                       // SGPR*VGPR
      const float r    = fmaxf(S0 - melt, 0.0f);        // S0 - Sm
      const float Sm   = S0 - r;                        // min(S0, melt)
      const float d    = fmaf(Pl, gi, fmaf(Ev, nge, Sm));
      S0 = r + Ps;
      const float z  = H0 + d;
      const float Hh = fmaxf(z, 0.0f);                      // H
      const float M  = __builtin_amdgcn_fmed3f(z, 0.0f, gl);  // min(H, gl)
      H0 = fminf(fmaf(mgo, M, Hh), gl);                     // min(H-go*M, gl)
      G  = fmaf(kb1m, G, gbgo * M);                         // pre-drained G
      yw[u * YPAD_] = fmaf(c2, G, fmaf(c1, M, ga * Hh));
    }

    // ---- transposed reduction: lane t' sums row t' (bank=(t'+h)%32, free);
    // same-wave DS ordering makes the writes above visible without a barrier
    float r0 = 0.0f, r1 = 0.0f, r2 = 0.0f, r3 = 0.0f;
#pragma unroll
    for (int h = 0; h < CH_; h += 4) {
      r0 += yr[h + 0];
      r1 += yr[h + 1];
      r2 += yr[h + 2];
      r3 += yr[h + 3];
    }
    const int t_out = c * CH_ + lane;
    if (t_out < NT_) out[t_out * NS_ + site] = ((r0 + r1) + (r2 + r3)) + qb;

    // next chunk's met into lane-registers (from the prefetched x)
    mm = compute_met(xnext);
  }
}

extern "C" void kernel_launch(void* const* d_in, const int* in_sizes, int n_in,
                              void* d_out, int out_size, void* d_ws, size_t ws_size,
                              hipStream_t stream) {
  const float* x    = (const float*)d_in[0];
  const float* xc   = (const float*)d_in[1];
  const float* fc_w = (const float*)d_in[2];
  const float* fc_b = (const float*)d_in[3];
  float* out = (float*)d_out;

  // 1024 sites, one wave each; 4 waves/block -> 256 blocks, ~1 wave/SIMD.
  hipLaunchKernelGGL(waternet_scan, dim3(NS_ / 4), dim3(256), 0, stream,
                     x, xc, fc_w, fc_b, out);
}